// Round 10
// baseline (1118.364 us; speedup 1.0000x reference)
//
#include <hip/hip_runtime.h>
#include <float.h>

// RVQ inference via MFMA: B=16, C=64, N=4096, Q=8, K=8192, fp32 in/out.
// Round-15 deltas vs round-14 (1109us; occ 34, VALUBusy 72.5, MfmaUtil 21):
//  - Counter-model fix: static issue accounting (155cy/wave-ktile x 4 waves
//    = 22% per SIMD) vs VALUBusy 72.5 => VALUBusy is CU-level any-SIMD-busy.
//    Per-SIMD issue ~25%: still latency-bound. Two exposed stalls/ktile:
//    vmcnt cover only half a body (dbuf x2-unroll), ds_read->MFMA lgkm
//    ~130cy.
//  - Fix: REGISTER-PIPELINED A-tiles. Each iter: stage t+2 into the LDS buf
//    freed by regs; compute tile t from regs; vmcnt(3) (full-body-old stage);
//    ds_read tile t+1 into fresh regs (used next iter => lgkm hidden under
//    pack). Both stalls leave the critical path. +~20 VGPR, LDS unchanged.
//  - Redundant per-wave merge: ALL waves compute all 64 points' top-4 merge
//    + tiered rescore from red_p (deterministic => identical K1 everywhere).
//    bk becomes lane-local (bk_sh gone); merge phase runs on 4 waves not 1.
//  - cvt_pk B-encode: v_cvt_pk_bf16_f32 (RTNE) x8 per q replaces ~64-op
//    bit-twiddle bf16 rounding.
//  - Numerics UNCHANGED (R12-proven): hi-only GEMM, per-quad packed 11-bit
//    top-3, 4-wave top-4 merge, tiered TAU=0.2 exact-fp32 rescore.
// ws: shalf (QK f32) | WH (QKC bf16-hi u16) | WL (unused, overrun pad) | loss.

typedef float f32x4 __attribute__((ext_vector_type(4)));
typedef short s16x8 __attribute__((ext_vector_type(8)));

constexpr int Bn=16, Cn=64, Nn=4096, Qn=8, Kn=8192;
constexpr int P=64;                     // points per block
constexpr int NPB = Nn/P;               // 64 n-blocks per batch row
constexpr int NBLK = Bn*Nn/P;           // 1024 blocks = exactly 4/CU
constexpr float TAU = 0.2f;             // rescore margin (~9.5 sigma)
constexpr int TILE_B = 2304;            // 2KB WH + 256B sv
constexpr size_t SH_F = (size_t)Qn*Kn;
constexpr size_t W_U  = (size_t)Qn*Kn*Cn;
// staging cursor jumps (bytes): end of a wave's 2048-code quarter -> start of
// next q's quarter
constexpr long QJ_H = (long)Kn*Cn*2 - 128L*2048;
constexpr long QJ_S = (long)Kn*4    - 128L*64;

union U8 { s16x8 v; unsigned short u[8]; };
union U32V { unsigned u[4]; s16x8 v; };

__device__ __forceinline__ unsigned short bf_rtne(float x){
  unsigned int u = __float_as_uint(x);
  unsigned int r = (u + 0x7fffu + ((u>>16)&1u)) >> 16;
  return (unsigned short)r;
}

__device__ __forceinline__ unsigned cvt_pk_bf16(float a, float b){
  unsigned r;
  asm("v_cvt_pk_bf16_f32 %0, %1, %2" : "=v"(r) : "v"(a), "v"(b));
  return r;
}

__device__ __forceinline__ void gl16(const void* g, void* l){
  __builtin_amdgcn_global_load_lds(
      (const __attribute__((address_space(1))) unsigned int*)g,
      (      __attribute__((address_space(3))) unsigned int*)l, 16, 0, 0);
}
__device__ __forceinline__ void gl4(const void* g, void* l){
  __builtin_amdgcn_global_load_lds(
      (const __attribute__((address_space(1))) unsigned int*)g,
      (      __attribute__((address_space(3))) unsigned int*)l, 4, 0, 0);
}

// Stage one 16-code tile (WH 2KB | sv 256B). lds/spH/spS wave-uniform; the
// per-lane global SOURCE column carries the reader's XOR involution
// col' = col ^ ((row&7)<<4).  3 VMEM ops per stage (vmcnt accounting).
__device__ __forceinline__ void stage_tile(const char* spH, const char* spS,
                                           char* lds, int lane){
  int rl   = lane>>3;
  int scol = ((lane&7) ^ rl) << 4;
  const char* gH = spH + (size_t)rl*128 + (size_t)scol;
  gl16(gH,        lds);
  gl16(gH + 1024, lds + 1024);
  gl4 (spS + (size_t)(lane & 15)*4, lds + 2048);
}

__global__ __launch_bounds__(256) void prep_kernel(const float* __restrict__ cb,
    float* __restrict__ shalf, unsigned short* __restrict__ WH,
    unsigned short* __restrict__ WL, float* __restrict__ loss){
  int r = blockIdx.x*256 + threadIdx.x;
  if (r==0) *loss = 0.f;
  const float* row = cb + (size_t)r*Cn;
  float sq = 0.f;
  for (int c=0;c<Cn;++c){
    float v = row[c]; sq = fmaf(v,v,sq);
    WH[(size_t)r*Cn+c] = bf_rtne(v);
  }
  shalf[r] = -0.5f*sq;
}

__global__ __launch_bounds__(256)
__attribute__((amdgpu_waves_per_eu(4)))
void rvq_kernel(
    const float* __restrict__ x, const float* __restrict__ cb,
    const float* __restrict__ shalf,
    const unsigned short* __restrict__ WH, const unsigned short* __restrict__ WL,
    float* __restrict__ out, float* __restrict__ loss_acc){
  __shared__ float4 RES4[P*16];              // 16KB: res[p][g^(p&15)]
  __shared__ __align__(16) char ABUF[4][2][TILE_B]; // wave x dbuf (18KB)
  __shared__ float  red_p1[4][P];            // packed (score|k11) per wave
  __shared__ float  red_p2[4][P];
  __shared__ float  red_p3[4][P];
  __shared__ float  lsum[4];

  const int tid  = threadIdx.x;
  const int wave = tid>>6, lane = tid&63;
  const int quad = lane>>4, l16 = lane&15;
  const int b    = blockIdx.x / NPB;
  const int n0   = (blockIdx.x % NPB)*P;
  const int uwave = __builtin_amdgcn_readfirstlane(wave);

  { // ---- RES init from x[B,C,N] (coalesced over p) ----
    int p = tid & (P-1), hc = tid>>6;
    const float* xb = x + ((size_t)b*Cn)*Nn + n0 + p;
#pragma unroll
    for (int l=0;l<4;++l){
      int g = hc*4 + l;
      float4 v;
      v.x = xb[(size_t)(4*g+0)*Nn]; v.y = xb[(size_t)(4*g+1)*Nn];
      v.z = xb[(size_t)(4*g+2)*Nn]; v.w = xb[(size_t)(4*g+3)*Nn];
      RES4[p*16 + (g ^ (p&15))] = v;
    }
  }
  // staging cursors (scalar): start at this wave's quarter of q=0
  const char* spH = (const char*)WH + (size_t)uwave*2048*128;
  const char* spS = (const char*)shalf + (size_t)uwave*2048*4;
  char* const buf0 = &ABUF[uwave][0][0];
  char* const buf1 = &ABUF[uwave][1][0];
  // prologue: stage tiles 0,1 into buf0,buf1
  stage_tile(spH, spS, buf0, lane); spH += 2048; spS += 64;
  stage_tile(spH, spS, buf1, lane); spH += 2048; spS += 64;
  int cstg = 2;
  __syncthreads();                           // drains vmcnt + RES4 ready

  // ---- A-register preload: tile 0 from buf0 ----
  const int sw  = (l16&7)<<4;
  const int rc0 = l16*128 + ((quad*16) ^ sw);
  const int rcS = 2048 + quad*16;
  s16x8 Ah0 = *(const s16x8*)(buf0 + rc0);
  s16x8 Ah1 = *(const s16x8*)(buf0 + (rc0 ^ 64));
  f32x4 sv  = *(const f32x4*)(buf0 + rcS);
  char* bufP = buf1;                         // holds next tile's DMA
  char* bufS = buf0;                         // next stage destination

  float loss_pt = 0.f;

  for (int q=0;q<Qn;++q){
    const float* sqq = shalf + (size_t)q*Kn;

    // ---- B-frags (4 ptiles, bf16-hi residual) via v_cvt_pk_bf16_f32 ----
    s16x8 Bh[4][2];
#pragma unroll
    for (int pt=0; pt<4; ++pt){
      int p = pt*16 + l16;
#pragma unroll
      for (int s=0;s<2;++s){
        int g0 = 8*s + quad*2;
        float4 ra = RES4[p*16 + ((g0  ) ^ (p&15))];
        float4 rb = RES4[p*16 + ((g0+1) ^ (p&15))];
        U32V h;
        h.u[0] = cvt_pk_bf16(ra.x, ra.y);
        h.u[1] = cvt_pk_bf16(ra.z, ra.w);
        h.u[2] = cvt_pk_bf16(rb.x, rb.y);
        h.u[3] = cvt_pk_bf16(rb.z, rb.w);
        Bh[pt][s] = h.v;
      }
    }

    // ---- scan this wave's 2048-code quarter; packed top-3 per point ----
    float s1[4], s2[4], s3[4];
#pragma unroll
    for (int pt=0;pt<4;++pt){ s1[pt]=-FLT_MAX; s2[pt]=-FLT_MAX; s3[pt]=-FLT_MAX; }
    unsigned kloc = (unsigned)(quad<<2);

    for (int kt=0; kt<128; ++kt){
      // stage tile t+2 into the LDS buffer freed by the register copy
      stage_tile(spH, spS, bufS, lane);
      spH += 2048; spS += 64;
      if (++cstg == 128){ cstg = 0; spH += QJ_H; spS += QJ_S; }

      // compute tile t from registers (independent of the wait below)
      f32x4 a[4];
#pragma unroll
      for (int pt=0;pt<4;++pt)
        a[pt] = __builtin_amdgcn_mfma_f32_16x16x32_bf16(Ah0, Bh[pt][0], sv, 0,0,0);
#pragma unroll
      for (int pt=0;pt<4;++pt)
        a[pt] = __builtin_amdgcn_mfma_f32_16x16x32_bf16(Ah1, Bh[pt][1], a[pt], 0,0,0);

      // wait tile t+1's DMA (issued one FULL body ago), read it into regs;
      // results used next iter => lgkm latency hides under the pack below.
      asm volatile("s_waitcnt vmcnt(3)" ::: "memory");
      s16x8 nAh0 = *(const s16x8*)(bufP + rc0);
      s16x8 nAh1 = *(const s16x8*)(bufP + (rc0 ^ 64));
      f32x4 nsv  = *(const f32x4*)(bufP + rcS);

      // packed top-3 update: (and|or) + fmax + 2x fmed3 per score
#pragma unroll
      for (int pt=0;pt<4;++pt){
#pragma unroll
        for (int r=0;r<4;++r){
          float pv = __uint_as_float((__float_as_uint(a[pt][r]) & 0xFFFFF800u)
                                     | (kloc + (unsigned)r));
          float n2 = __builtin_amdgcn_fmed3f(pv, s1[pt], s2[pt]);
          float n3 = __builtin_amdgcn_fmed3f(pv, s2[pt], s3[pt]);
          s1[pt] = fmaxf(s1[pt], pv); s2[pt] = n2; s3[pt] = n3;
        }
      }
      kloc += 16;
      Ah0 = nAh0; Ah1 = nAh1; sv = nsv;
      { char* t = bufS; bufS = bufP; bufP = t; }
    }

    // ---- cross-quad top-3 merge in packed domain ----
#pragma unroll
    for (int pt=0;pt<4;++pt){
#pragma unroll
      for (int m=16; m<=32; m<<=1){
        float o1 = __shfl_xor(s1[pt], m, 64);
        float o2 = __shfl_xor(s2[pt], m, 64);
        float o3 = __shfl_xor(s3[pt], m, 64);
        float A  = fminf(s1[pt], o1);
        float n1 = fmaxf(s1[pt], o1);
        float Bv = fmaxf(s2[pt], o2);
        float D  = fmaxf(s3[pt], o3);
        float n2 = fmaxf(A, Bv);
        float n3 = fmaxf(fminf(A, Bv), D);
        s1[pt]=n1; s2[pt]=n2; s3[pt]=n3;
      }
      if (quad==0){
        int p = pt*16 + l16;
        red_p1[wave][p]=s1[pt]; red_p2[wave][p]=s2[pt]; red_p3[wave][p]=s3[pt];
      }
    }
    __syncthreads();

    // ---- redundant 4-wave TOP-4 merge + tiered rescore: EVERY wave, lane=point
    int bk;
    {
      const int pl = lane;                   // point index 0..63
      float S1=-FLT_MAX,S2=-FLT_MAX,S3=-FLT_MAX,S4=-FLT_MAX;
      int   W1=0,W2=0,W3=0,W4=0;
#pragma unroll
      for (int w=0; w<4; ++w){
        float o[3] = { red_p1[w][pl], red_p2[w][pl], red_p3[w][pl] };
#pragma unroll
        for (int j=0;j<3;++j){
          float v = o[j];
          if (v > S1){ S4=S3;W4=W3; S3=S2;W3=W2; S2=S1;W2=W1; S1=v;W1=w; }
          else if (v > S2){ S4=S3;W4=W3; S3=S2;W3=W2; S2=v;W2=w; }
          else if (v > S3){ S4=S3;W4=W3; S3=v;W3=w; }
          else if (v > S4){ S4=v;W4=w; }
        }
      }
      int K1 = (W1<<11) | (int)(__float_as_uint(S1) & 2047u);
      if (S1 - S2 < TAU){   // near-tie: exact fp32 rescore, tiered to top-4
        int K2 = (W2<<11) | (int)(__float_as_uint(S2) & 2047u);
        float d1 = sqq[K1], d2 = sqq[K2];
        const float4* r1 = (const float4*)(cb + ((size_t)q*Kn + K1)*Cn);
        const float4* r2 = (const float4*)(cb + ((size_t)q*Kn + K2)*Cn);
#pragma unroll
        for (int g=0; g<16; ++g){
          float4 rv = RES4[pl*16 + (g ^ (pl&15))];
          float4 c1 = r1[g], c2 = r2[g];
          d1=fmaf(rv.x,c1.x,d1); d1=fmaf(rv.y,c1.y,d1);
          d1=fmaf(rv.z,c1.z,d1); d1=fmaf(rv.w,c1.w,d1);
          d2=fmaf(rv.x,c2.x,d2); d2=fmaf(rv.y,c2.y,d2);
          d2=fmaf(rv.z,c2.z,d2); d2=fmaf(rv.w,c2.w,d2);
        }
        if ( (d2 > d1) || (d2==d1 && K2<K1) ){ K1 = K2; d1 = d2; }
        if (S1 - S3 < TAU){
          int K3 = (W3<<11) | (int)(__float_as_uint(S3) & 2047u);
          float d3 = sqq[K3];
          const float4* r3 = (const float4*)(cb + ((size_t)q*Kn + K3)*Cn);
#pragma unroll
          for (int g=0; g<16; ++g){
            float4 rv = RES4[pl*16 + (g ^ (pl&15))];
            float4 c3 = r3[g];
            d3=fmaf(rv.x,c3.x,d3); d3=fmaf(rv.y,c3.y,d3);
            d3=fmaf(rv.z,c3.z,d3); d3=fmaf(rv.w,c3.w,d3);
          }
          if ( (d3 > d1) || (d3==d1 && K3<K1) ){ K1 = K3; d1 = d3; }
          if (S1 - S4 < TAU){
            int K4 = (W4<<11) | (int)(__float_as_uint(S4) & 2047u);
            float d4 = sqq[K4];
            const float4* r4 = (const float4*)(cb + ((size_t)q*Kn + K4)*Cn);
#pragma unroll
            for (int g=0; g<16; ++g){
              float4 rv = RES4[pl*16 + (g ^ (pl&15))];
              float4 c4 = r4[g];
              d4=fmaf(rv.x,c4.x,d4); d4=fmaf(rv.y,c4.y,d4);
              d4=fmaf(rv.z,c4.z,d4); d4=fmaf(rv.w,c4.w,d4);
            }
            if ( (d4 > d1) || (d4==d1 && K4<K1) ) K1 = K4;
          }
        }
      }
      if (wave==0)
        out[(size_t)(Bn*Cn*Nn) + (size_t)(b*Nn + n0 + pl)*Qn + q] = (float)K1;
      bk = K1;
    }
    __syncthreads();   // all rescore reads of RES4 done before updates

    // ---- residual update (exact fp32; bk is lane-local) + loss ----
    {
      int p = lane, hc = wave;
      const float4* crow = (const float4*)(cb + ((size_t)q*Kn + bk)*Cn) + hc*4;
#pragma unroll
      for (int l=0;l<4;++l){
        int g = hc*4 + l;
        float4 v = crow[l];
        int idx = p*16 + (g ^ (p&15));
        float4 rv = RES4[idx];
        rv.x-=v.x; rv.y-=v.y; rv.z-=v.z; rv.w-=v.w;
        RES4[idx]=rv;
        loss_pt = fmaf(rv.x,rv.x,loss_pt); loss_pt = fmaf(rv.y,rv.y,loss_pt);
        loss_pt = fmaf(rv.z,rv.z,loss_pt); loss_pt = fmaf(rv.w,rv.w,loss_pt);
      }
    }
    __syncthreads();
  } // q

  // ---- quantized = x - final residual (coalesced over p) ----
  {
    int p = tid & (P-1), hc = tid>>6;
    const float* xb = x + ((size_t)b*Cn)*Nn + n0 + p;
    float*       ob = out + ((size_t)b*Cn)*Nn + n0 + p;
#pragma unroll
    for (int l=0;l<4;++l){
      int g = hc*4+l, c = 4*g;
      float4 rv = RES4[p*16 + (g ^ (p&15))];
      ob[(size_t)(c+0)*Nn] = xb[(size_t)(c+0)*Nn] - rv.x;
      ob[(size_t)(c+1)*Nn] = xb[(size_t)(c+1)*Nn] - rv.y;
      ob[(size_t)(c+2)*Nn] = xb[(size_t)(c+2)*Nn] - rv.z;
      ob[(size_t)(c+3)*Nn] = xb[(size_t)(c+3)*Nn] - rv.w;
    }
  }
  float s = loss_pt;
#pragma unroll
  for (int off=32; off>0; off>>=1) s += __shfl_down(s, off, 64);
  if (lane==0) lsum[wave]=s;
  __syncthreads();
  if (tid==0) atomicAdd(loss_acc, lsum[0]+lsum[1]+lsum[2]+lsum[3]);
}

__global__ void final_kernel(const float* __restrict__ loss_acc,
                             float* __restrict__ out){
  out[(size_t)Bn*Cn*Nn + (size_t)Bn*Nn*Qn] =
      loss_acc[0] * (1.0f / ((float)Qn * Bn * Nn * Cn));
}

extern "C" void kernel_launch(void* const* d_in, const int* in_sizes, int n_in,
                              void* d_out, int out_size, void* d_ws, size_t ws_size,
                              hipStream_t stream) {
  const float* x  = (const float*)d_in[0];
  const float* cb = (const float*)d_in[1];
  float* out = (float*)d_out;
  float* ws  = (float*)d_ws;

  float* shalf = ws;
  unsigned short* WH = (unsigned short*)(ws + SH_F);
  unsigned short* WL = WH + W_U;           // unused (staging-overrun pad)
  float* loss = (float*)(WL + W_U);

  hipLaunchKernelGGL(prep_kernel, dim3((Qn*Kn)/256), dim3(256), 0, stream,
                     cb, shalf, WH, WL, loss);
  hipLaunchKernelGGL(rvq_kernel, dim3(NBLK), dim3(256), 0, stream,
                     x, cb, shalf, WH, WL, out, loss);
  hipLaunchKernelGGL(final_kernel, dim3(1), dim3(1), 0, stream, loss, out);
}

// Round 11
// 1071.024 us; speedup vs baseline: 1.0442x; 1.0442x over previous
//
#include <hip/hip_runtime.h>
#include <float.h>

// RVQ inference via MFMA: B=16, C=64, N=4096, Q=8, K=8192, fp32 in/out.
// Round-16 delta vs round-15 (1118us, NULL vs R14 -- confounded experiment):
//  - R15 shipped with VGPR_Count=64: waves_per_eu(4) sets only a MINIMUM, so
//    the allocator targeted 8 waves/EU (64 regs) although LDS caps residency
//    at 4 waves/SIMD. The ~105-reg live set can't fit 64 -> the A-register
//    pipeline was rematerialized into just-in-time ds_reads == R14's binary.
//    Third allocator trap of the session (R8, R13 tail, now R15).
//  - Fix: waves_per_eu(4,4) pins min=max=4 -> 128-VGPR budget; the register
//    pipeline (stage t+2 / compute t from regs / vmcnt(3)+ds_read t+1) can
//    actually materialize. Everything else byte-identical to R15.
//  - Gate: VGPR_Count >= ~96 proves the experiment ran. If yes and dur still
//    ~1100: latency-convoy theory dead -> attack issue count next.
// ws: shalf (QK f32) | WH (QKC bf16-hi u16) | WL (unused, overrun pad) | loss.

typedef float f32x4 __attribute__((ext_vector_type(4)));
typedef short s16x8 __attribute__((ext_vector_type(8)));

constexpr int Bn=16, Cn=64, Nn=4096, Qn=8, Kn=8192;
constexpr int P=64;                     // points per block
constexpr int NPB = Nn/P;               // 64 n-blocks per batch row
constexpr int NBLK = Bn*Nn/P;           // 1024 blocks = exactly 4/CU
constexpr float TAU = 0.2f;             // rescore margin (~9.5 sigma)
constexpr int TILE_B = 2304;            // 2KB WH + 256B sv
constexpr size_t SH_F = (size_t)Qn*Kn;
constexpr size_t W_U  = (size_t)Qn*Kn*Cn;
constexpr long QJ_H = (long)Kn*Cn*2 - 128L*2048;
constexpr long QJ_S = (long)Kn*4    - 128L*64;

union U8 { s16x8 v; unsigned short u[8]; };
union U32V { unsigned u[4]; s16x8 v; };

__device__ __forceinline__ unsigned short bf_rtne(float x){
  unsigned int u = __float_as_uint(x);
  unsigned int r = (u + 0x7fffu + ((u>>16)&1u)) >> 16;
  return (unsigned short)r;
}

__device__ __forceinline__ unsigned cvt_pk_bf16(float a, float b){
  unsigned r;
  asm("v_cvt_pk_bf16_f32 %0, %1, %2" : "=v"(r) : "v"(a), "v"(b));
  return r;
}

__device__ __forceinline__ void gl16(const void* g, void* l){
  __builtin_amdgcn_global_load_lds(
      (const __attribute__((address_space(1))) unsigned int*)g,
      (      __attribute__((address_space(3))) unsigned int*)l, 16, 0, 0);
}
__device__ __forceinline__ void gl4(const void* g, void* l){
  __builtin_amdgcn_global_load_lds(
      (const __attribute__((address_space(1))) unsigned int*)g,
      (      __attribute__((address_space(3))) unsigned int*)l, 4, 0, 0);
}

// Stage one 16-code tile (WH 2KB | sv 256B). lds/spH/spS wave-uniform; the
// per-lane global SOURCE column carries the reader's XOR involution
// col' = col ^ ((row&7)<<4).  3 VMEM ops per stage (vmcnt accounting).
__device__ __forceinline__ void stage_tile(const char* spH, const char* spS,
                                           char* lds, int lane){
  int rl   = lane>>3;
  int scol = ((lane&7) ^ rl) << 4;
  const char* gH = spH + (size_t)rl*128 + (size_t)scol;
  gl16(gH,        lds);
  gl16(gH + 1024, lds + 1024);
  gl4 (spS + (size_t)(lane & 15)*4, lds + 2048);
}

__global__ __launch_bounds__(256) void prep_kernel(const float* __restrict__ cb,
    float* __restrict__ shalf, unsigned short* __restrict__ WH,
    unsigned short* __restrict__ WL, float* __restrict__ loss){
  int r = blockIdx.x*256 + threadIdx.x;
  if (r==0) *loss = 0.f;
  const float* row = cb + (size_t)r*Cn;
  float sq = 0.f;
  for (int c=0;c<Cn;++c){
    float v = row[c]; sq = fmaf(v,v,sq);
    WH[(size_t)r*Cn+c] = bf_rtne(v);
  }
  shalf[r] = -0.5f*sq;
}

__global__ __launch_bounds__(256)
__attribute__((amdgpu_waves_per_eu(4,4)))
void rvq_kernel(
    const float* __restrict__ x, const float* __restrict__ cb,
    const float* __restrict__ shalf,
    const unsigned short* __restrict__ WH, const unsigned short* __restrict__ WL,
    float* __restrict__ out, float* __restrict__ loss_acc){
  __shared__ float4 RES4[P*16];              // 16KB: res[p][g^(p&15)]
  __shared__ __align__(16) char ABUF[4][2][TILE_B]; // wave x dbuf (18KB)
  __shared__ float  red_p1[4][P];            // packed (score|k11) per wave
  __shared__ float  red_p2[4][P];
  __shared__ float  red_p3[4][P];
  __shared__ float  lsum[4];

  const int tid  = threadIdx.x;
  const int wave = tid>>6, lane = tid&63;
  const int quad = lane>>4, l16 = lane&15;
  const int b    = blockIdx.x / NPB;
  const int n0   = (blockIdx.x % NPB)*P;
  const int uwave = __builtin_amdgcn_readfirstlane(wave);

  { // ---- RES init from x[B,C,N] (coalesced over p) ----
    int p = tid & (P-1), hc = tid>>6;
    const float* xb = x + ((size_t)b*Cn)*Nn + n0 + p;
#pragma unroll
    for (int l=0;l<4;++l){
      int g = hc*4 + l;
      float4 v;
      v.x = xb[(size_t)(4*g+0)*Nn]; v.y = xb[(size_t)(4*g+1)*Nn];
      v.z = xb[(size_t)(4*g+2)*Nn]; v.w = xb[(size_t)(4*g+3)*Nn];
      RES4[p*16 + (g ^ (p&15))] = v;
    }
  }
  // staging cursors (scalar): start at this wave's quarter of q=0
  const char* spH = (const char*)WH + (size_t)uwave*2048*128;
  const char* spS = (const char*)shalf + (size_t)uwave*2048*4;
  char* const buf0 = &ABUF[uwave][0][0];
  char* const buf1 = &ABUF[uwave][1][0];
  // prologue: stage tiles 0,1 into buf0,buf1
  stage_tile(spH, spS, buf0, lane); spH += 2048; spS += 64;
  stage_tile(spH, spS, buf1, lane); spH += 2048; spS += 64;
  int cstg = 2;
  __syncthreads();                           // drains vmcnt + RES4 ready

  // ---- A-register preload: tile 0 from buf0 ----
  const int sw  = (l16&7)<<4;
  const int rc0 = l16*128 + ((quad*16) ^ sw);
  const int rcS = 2048 + quad*16;
  s16x8 Ah0 = *(const s16x8*)(buf0 + rc0);
  s16x8 Ah1 = *(const s16x8*)(buf0 + (rc0 ^ 64));
  f32x4 sv  = *(const f32x4*)(buf0 + rcS);
  char* bufP = buf1;                         // holds next tile's DMA
  char* bufS = buf0;                         // next stage destination

  float loss_pt = 0.f;

  for (int q=0;q<Qn;++q){
    const float* sqq = shalf + (size_t)q*Kn;

    // ---- B-frags (4 ptiles, bf16-hi residual) via v_cvt_pk_bf16_f32 ----
    s16x8 Bh[4][2];
#pragma unroll
    for (int pt=0; pt<4; ++pt){
      int p = pt*16 + l16;
#pragma unroll
      for (int s=0;s<2;++s){
        int g0 = 8*s + quad*2;
        float4 ra = RES4[p*16 + ((g0  ) ^ (p&15))];
        float4 rb = RES4[p*16 + ((g0+1) ^ (p&15))];
        U32V h;
        h.u[0] = cvt_pk_bf16(ra.x, ra.y);
        h.u[1] = cvt_pk_bf16(ra.z, ra.w);
        h.u[2] = cvt_pk_bf16(rb.x, rb.y);
        h.u[3] = cvt_pk_bf16(rb.z, rb.w);
        Bh[pt][s] = h.v;
      }
    }

    // ---- scan this wave's 2048-code quarter; packed top-3 per point ----
    float s1[4], s2[4], s3[4];
#pragma unroll
    for (int pt=0;pt<4;++pt){ s1[pt]=-FLT_MAX; s2[pt]=-FLT_MAX; s3[pt]=-FLT_MAX; }
    unsigned kloc = (unsigned)(quad<<2);

    for (int kt=0; kt<128; ++kt){
      // stage tile t+2 into the LDS buffer freed by the register copy
      stage_tile(spH, spS, bufS, lane);
      spH += 2048; spS += 64;
      if (++cstg == 128){ cstg = 0; spH += QJ_H; spS += QJ_S; }

      // compute tile t from registers (independent of the wait below)
      f32x4 a[4];
#pragma unroll
      for (int pt=0;pt<4;++pt)
        a[pt] = __builtin_amdgcn_mfma_f32_16x16x32_bf16(Ah0, Bh[pt][0], sv, 0,0,0);
#pragma unroll
      for (int pt=0;pt<4;++pt)
        a[pt] = __builtin_amdgcn_mfma_f32_16x16x32_bf16(Ah1, Bh[pt][1], a[pt], 0,0,0);

      // wait tile t+1's DMA (issued one FULL body ago), read it into regs;
      // results used next iter => lgkm latency hides under the pack below.
      asm volatile("s_waitcnt vmcnt(3)" ::: "memory");
      s16x8 nAh0 = *(const s16x8*)(bufP + rc0);
      s16x8 nAh1 = *(const s16x8*)(bufP + (rc0 ^ 64));
      f32x4 nsv  = *(const f32x4*)(bufP + rcS);

      // packed top-3 update: (and|or) + fmax + 2x fmed3 per score
#pragma unroll
      for (int pt=0;pt<4;++pt){
#pragma unroll
        for (int r=0;r<4;++r){
          float pv = __uint_as_float((__float_as_uint(a[pt][r]) & 0xFFFFF800u)
                                     | (kloc + (unsigned)r));
          float n2 = __builtin_amdgcn_fmed3f(pv, s1[pt], s2[pt]);
          float n3 = __builtin_amdgcn_fmed3f(pv, s2[pt], s3[pt]);
          s1[pt] = fmaxf(s1[pt], pv); s2[pt] = n2; s3[pt] = n3;
        }
      }
      kloc += 16;
      Ah0 = nAh0; Ah1 = nAh1; sv = nsv;
      { char* t = bufS; bufS = bufP; bufP = t; }
    }

    // ---- cross-quad top-3 merge in packed domain ----
#pragma unroll
    for (int pt=0;pt<4;++pt){
#pragma unroll
      for (int m=16; m<=32; m<<=1){
        float o1 = __shfl_xor(s1[pt], m, 64);
        float o2 = __shfl_xor(s2[pt], m, 64);
        float o3 = __shfl_xor(s3[pt], m, 64);
        float A  = fminf(s1[pt], o1);
        float n1 = fmaxf(s1[pt], o1);
        float Bv = fmaxf(s2[pt], o2);
        float D  = fmaxf(s3[pt], o3);
        float n2 = fmaxf(A, Bv);
        float n3 = fmaxf(fminf(A, Bv), D);
        s1[pt]=n1; s2[pt]=n2; s3[pt]=n3;
      }
      if (quad==0){
        int p = pt*16 + l16;
        red_p1[wave][p]=s1[pt]; red_p2[wave][p]=s2[pt]; red_p3[wave][p]=s3[pt];
      }
    }
    __syncthreads();

    // ---- redundant 4-wave TOP-4 merge + tiered rescore: EVERY wave, lane=point
    int bk;
    {
      const int pl = lane;                   // point index 0..63
      float S1=-FLT_MAX,S2=-FLT_MAX,S3=-FLT_MAX,S4=-FLT_MAX;
      int   W1=0,W2=0,W3=0,W4=0;
#pragma unroll
      for (int w=0; w<4; ++w){
        float o[3] = { red_p1[w][pl], red_p2[w][pl], red_p3[w][pl] };
#pragma unroll
        for (int j=0;j<3;++j){
          float v = o[j];
          if (v > S1){ S4=S3;W4=W3; S3=S2;W3=W2; S2=S1;W2=W1; S1=v;W1=w; }
          else if (v > S2){ S4=S3;W4=W3; S3=S2;W3=W2; S2=v;W2=w; }
          else if (v > S3){ S4=S3;W4=W3; S3=v;W3=w; }
          else if (v > S4){ S4=v;W4=w; }
        }
      }
      int K1 = (W1<<11) | (int)(__float_as_uint(S1) & 2047u);
      if (S1 - S2 < TAU){   // near-tie: exact fp32 rescore, tiered to top-4
        int K2 = (W2<<11) | (int)(__float_as_uint(S2) & 2047u);
        float d1 = sqq[K1], d2 = sqq[K2];
        const float4* r1 = (const float4*)(cb + ((size_t)q*Kn + K1)*Cn);
        const float4* r2 = (const float4*)(cb + ((size_t)q*Kn + K2)*Cn);
#pragma unroll
        for (int g=0; g<16; ++g){
          float4 rv = RES4[pl*16 + (g ^ (pl&15))];
          float4 c1 = r1[g], c2 = r2[g];
          d1=fmaf(rv.x,c1.x,d1); d1=fmaf(rv.y,c1.y,d1);
          d1=fmaf(rv.z,c1.z,d1); d1=fmaf(rv.w,c1.w,d1);
          d2=fmaf(rv.x,c2.x,d2); d2=fmaf(rv.y,c2.y,d2);
          d2=fmaf(rv.z,c2.z,d2); d2=fmaf(rv.w,c2.w,d2);
        }
        if ( (d2 > d1) || (d2==d1 && K2<K1) ){ K1 = K2; d1 = d2; }
        if (S1 - S3 < TAU){
          int K3 = (W3<<11) | (int)(__float_as_uint(S3) & 2047u);
          float d3 = sqq[K3];
          const float4* r3 = (const float4*)(cb + ((size_t)q*Kn + K3)*Cn);
#pragma unroll
          for (int g=0; g<16; ++g){
            float4 rv = RES4[pl*16 + (g ^ (pl&15))];
            float4 c3 = r3[g];
            d3=fmaf(rv.x,c3.x,d3); d3=fmaf(rv.y,c3.y,d3);
            d3=fmaf(rv.z,c3.z,d3); d3=fmaf(rv.w,c3.w,d3);
          }
          if ( (d3 > d1) || (d3==d1 && K3<K1) ){ K1 = K3; d1 = d3; }
          if (S1 - S4 < TAU){
            int K4 = (W4<<11) | (int)(__float_as_uint(S4) & 2047u);
            float d4 = sqq[K4];
            const float4* r4 = (const float4*)(cb + ((size_t)q*Kn + K4)*Cn);
#pragma unroll
            for (int g=0; g<16; ++g){
              float4 rv = RES4[pl*16 + (g ^ (pl&15))];
              float4 c4 = r4[g];
              d4=fmaf(rv.x,c4.x,d4); d4=fmaf(rv.y,c4.y,d4);
              d4=fmaf(rv.z,c4.z,d4); d4=fmaf(rv.w,c4.w,d4);
            }
            if ( (d4 > d1) || (d4==d1 && K4<K1) ) K1 = K4;
          }
        }
      }
      if (wave==0)
        out[(size_t)(Bn*Cn*Nn) + (size_t)(b*Nn + n0 + pl)*Qn + q] = (float)K1;
      bk = K1;
    }
    __syncthreads();   // all rescore reads of RES4 done before updates

    // ---- residual update (exact fp32; bk is lane-local) + loss ----
    {
      int p = lane, hc = wave;
      const float4* crow = (const float4*)(cb + ((size_t)q*Kn + bk)*Cn) + hc*4;
#pragma unroll
      for (int l=0;l<4;++l){
        int g = hc*4 + l;
        float4 v = crow[l];
        int idx = p*16 + (g ^ (p&15));
        float4 rv = RES4[idx];
        rv.x-=v.x; rv.y-=v.y; rv.z-=v.z; rv.w-=v.w;
        RES4[idx]=rv;
        loss_pt = fmaf(rv.x,rv.x,loss_pt); loss_pt = fmaf(rv.y,rv.y,loss_pt);
        loss_pt = fmaf(rv.z,rv.z,loss_pt); loss_pt = fmaf(rv.w,rv.w,loss_pt);
      }
    }
    __syncthreads();
  } // q

  // ---- quantized = x - final residual (coalesced over p) ----
  {
    int p = tid & (P-1), hc = tid>>6;
    const float* xb = x + ((size_t)b*Cn)*Nn + n0 + p;
    float*       ob = out + ((size_t)b*Cn)*Nn + n0 + p;
#pragma unroll
    for (int l=0;l<4;++l){
      int g = hc*4+l, c = 4*g;
      float4 rv = RES4[p*16 + (g ^ (p&15))];
      ob[(size_t)(c+0)*Nn] = xb[(size_t)(c+0)*Nn] - rv.x;
      ob[(size_t)(c+1)*Nn] = xb[(size_t)(c+1)*Nn] - rv.y;
      ob[(size_t)(c+2)*Nn] = xb[(size_t)(c+2)*Nn] - rv.z;
      ob[(size_t)(c+3)*Nn] = xb[(size_t)(c+3)*Nn] - rv.w;
    }
  }
  float s = loss_pt;
#pragma unroll
  for (int off=32; off>0; off>>=1) s += __shfl_down(s, off, 64);
  if (lane==0) lsum[wave]=s;
  __syncthreads();
  if (tid==0) atomicAdd(loss_acc, lsum[0]+lsum[1]+lsum[2]+lsum[3]);
}

__global__ void final_kernel(const float* __restrict__ loss_acc,
                             float* __restrict__ out){
  out[(size_t)Bn*Cn*Nn + (size_t)Bn*Nn*Qn] =
      loss_acc[0] * (1.0f / ((float)Qn * Bn * Nn * Cn));
}

extern "C" void kernel_launch(void* const* d_in, const int* in_sizes, int n_in,
                              void* d_out, int out_size, void* d_ws, size_t ws_size,
                              hipStream_t stream) {
  const float* x  = (const float*)d_in[0];
  const float* cb = (const float*)d_in[1];
  float* out = (float*)d_out;
  float* ws  = (float*)d_ws;

  float* shalf = ws;
  unsigned short* WH = (unsigned short*)(ws + SH_F);
  unsigned short* WL = WH + W_U;           // unused (staging-overrun pad)
  float* loss = (float*)(WL + W_U);

  hipLaunchKernelGGL(prep_kernel, dim3((Qn*Kn)/256), dim3(256), 0, stream,
                     cb, shalf, WH, WL, loss);
  hipLaunchKernelGGL(rvq_kernel, dim3(NBLK), dim3(256), 0, stream,
                     x, cb, shalf, WH, WL, out, loss);
  hipLaunchKernelGGL(final_kernel, dim3(1), dim3(1), 0, stream, loss, out);
}